// Round 8
// baseline (343.150 us; speedup 1.0000x reference)
//
#include <hip/hip_runtime.h>
#include <hip/hip_bf16.h>
#include <math.h>
#include <stdint.h>

namespace {

constexpr int Bn  = 8;
constexpr int Nn  = 500;
constexpr int Qn  = 25;
constexpr int ENC = 512;
constexpr int DIN = 300;
constexpr int NCn = 70;
constexpr int NETn = 3;
constexpr int NLCAP = 96;   // neighbor-list capacity (mean 29.4, sigma 5.3 -> 12.7 sigma)

typedef __attribute__((ext_vector_type(8))) short bf16x8_t;
typedef __attribute__((ext_vector_type(4))) float f32x4_t;

__device__ __forceinline__ unsigned short f2bf(float f) {
    union { __hip_bfloat16 b; unsigned short u; } r;
    r.b = __float2bfloat16(f);
    return r.u;
}
__device__ __forceinline__ bf16x8_t cvt8(float4 f0, float4 f1) {
    union { bf16x8_t v; __hip_bfloat162 b[4]; } r;
    r.b[0] = __float22bfloat162_rn(make_float2(f0.x, f0.y));
    r.b[1] = __float22bfloat162_rn(make_float2(f0.z, f0.w));
    r.b[2] = __float22bfloat162_rn(make_float2(f1.x, f1.y));
    r.b[3] = __float22bfloat162_rn(make_float2(f1.z, f1.w));
    return r.v;
}
__device__ __forceinline__ float bf2f(unsigned short h) {
    unsigned int u = ((unsigned int)h) << 16;
    return __builtin_bit_cast(float, u);
}
__device__ __forceinline__ float sigmoidf_(float x) { return 1.0f / (1.0f + expf(-x)); }

// R20: async global->LDS, 16B per lane (dest = wave-uniform base + lane*16B).
typedef __attribute__((address_space(1))) const unsigned int g_u32;
typedef __attribute__((address_space(3))) unsigned int l_u32;
__device__ __forceinline__ void gld16(const void* g, void* l) {
    __builtin_amdgcn_global_load_lds((g_u32*)g, (l_u32*)l, 16, 0, 0);
}

// ---------------------------------------------------------------------------
// Fused prep: z=1 -> Asum; z=0 -> weight transposes.
__global__ __launch_bounds__(256) void prep_k(
    const float* __restrict__ adj, float* __restrict__ Asum,
    const float* __restrict__ Wn, const float* __restrict__ Wq,
    const float* __restrict__ Wh, const float* __restrict__ Wc,
    const float* __restrict__ W1,
    unsigned short* __restrict__ WnT, unsigned short* __restrict__ WqT,
    unsigned short* __restrict__ WhcT, unsigned short* __restrict__ WcHiT,
    unsigned short* __restrict__ W1T) {
    if (blockIdx.z == 1) {
        int bi = blockIdx.x * 2 + (threadIdx.x >> 7);
        if (bi >= Bn * Nn) return;
        int b = bi / Nn, i = bi - b * Nn;
        int j = (threadIdx.x & 127) * 4;
        float4 s = make_float4(0.f, 0.f, 0.f, 0.f);
        if (j < Nn) {
#pragma unroll
            for (int e = 0; e < NETn; ++e) {
                const float* p = adj + (((size_t)(b * NETn + e) * Nn) + i) * Nn + j;
                float4 v = *(const float4*)p;
                s.x += v.x; s.y += v.y; s.z += v.z; s.w += v.w;
            }
        }
        *(float4*)(Asum + ((size_t)bi) * 512 + j) = s;
        return;
    }
    __shared__ float tile[32][33];
    int x = blockIdx.x;
    const float* in; unsigned short* out; int K, N, Kpad, tx, ty;
    if (x < 160)       { in = Wn; out = WnT; K = DIN; N = ENC; Kpad = 320;
                         tx = x & 15; ty = x >> 4; }
    else if (x < 320)  { int l = x - 160; in = Wq; out = WqT; K = DIN; N = ENC;
                         Kpad = 320; tx = l & 15; ty = l >> 4; }
    else if (x < 576)  { int l = x - 320; in = Wh; out = WhcT; K = 512; N = ENC;
                         Kpad = 512; tx = l & 15; ty = l >> 4; }
    else if (x < 832)  { int l = x - 576; in = Wc + (size_t)512 * ENC;
                         out = WhcT + (size_t)512 * 512; K = 512; N = ENC;
                         Kpad = 512; tx = l & 15; ty = l >> 4; }
    else if (x < 1088) { int l = x - 832; in = Wc; out = WcHiT; K = 512; N = ENC;
                         Kpad = 512; tx = l & 15; ty = l >> 4; }
    else if (x < 1344) { int l = x - 1088; in = W1; out = W1T; K = 2048; N = 128;
                         Kpad = 2048; tx = l & 3; ty = l >> 2; }
    else return;
    int n0 = tx * 32, k0 = ty * 32;
    int ltx = threadIdx.x & 31, lty = threadIdx.x >> 5;
#pragma unroll
    for (int r = 0; r < 4; ++r) {
        int k = k0 + lty * 4 + r;
        int n = n0 + ltx;
        tile[lty * 4 + r][ltx] = (k < K && n < N) ? in[(size_t)k * N + n] : 0.0f;
    }
    __syncthreads();
#pragma unroll
    for (int r = 0; r < 4; ++r) {
        int n = n0 + lty * 4 + r;
        int k = k0 + ltx;
        if (n < N && k < Kpad) out[(size_t)n * Kpad + k] = f2bf(tile[ltx][lty * 4 + r]);
    }
}

// ---------------------------------------------------------------------------
// MFMA core, BK=64: 64x64 tile, 4 waves, double-buffered LDS.
// AMODE 0: A fp32 (Klim clamp).  AMODE 1: A bf16 (gld16 direct).
// AMODE 3 (R22): full-K=2048 concat-A for the final GEMM; per-64-step z-slice:
//   z=0: nc; z=1: A2(n2q); z=2: nc*n2q; z=3: nc*q2n[b].  lda must be 512.
template <int AMODE>
__device__ __forceinline__ void mfma_core(
    const float* __restrict__ A, const float* __restrict__ A2,
    const float* __restrict__ A3,
    const unsigned short* __restrict__ Abf,
    int lda, int Klim,
    const unsigned short* __restrict__ Bt, int ldb,
    int m0, int n0, int K, int Mlim,
    unsigned short* As, unsigned short* Bts, f32x4_t acc[2][2]) {
    const int t = threadIdx.x;
    const int lane = t & 63;
    const int w = t >> 6;
    const int sm = t >> 2;
    const int sp = t & 3;
    const int sq = sp ^ ((sm >> 1) & 3);
    const int arow = m0 + sm;
    const bool rowok = arow < Mlim;
    const int arowc = rowok ? arow : (Mlim - 1);
    const int wm = (w & 1) * 32, wn = (w >> 1) * 32;
    const int quad = lane >> 4, cidx = lane & 15;
    const int am0 = wm + cidx, am1 = wm + 16 + cidx;
    const int an0 = wn + cidx, an1 = wn + 16 + cidx;
    const int apo0 = am0 * 32 + (quad ^ ((am0 >> 1) & 3)) * 8;
    const int apo1 = am1 * 32 + (quad ^ ((am1 >> 1) & 3)) * 8;
    const int bpo0 = an0 * 32 + (quad ^ ((an0 >> 1) & 3)) * 8;
    const int bpo1 = an1 * 32 + (quad ^ ((an1 >> 1) & 3)) * 8;
    const int wbase = w * 512;  // shorts; wave-uniform LDS base

    const unsigned short* abase = (AMODE == 1) ? Abf + (size_t)arowc * lda : nullptr;
    const unsigned short* bbase = Bt + (size_t)(n0 + sm) * ldb;
    const int ko0 = sq * 8, ko1 = 32 + sq * 8;
    const float* q2nrow = (AMODE == 3 && A3 != nullptr)
                              ? A3 + (size_t)(arowc / Nn) * 512 : nullptr;

    float4 raf0, raf1, raf2, raf3;  // fp32 A reg staging
    auto stageAF = [&](int kg, float4& f0, float4& f1) {
        f0 = make_float4(0.f, 0.f, 0.f, 0.f);
        f1 = make_float4(0.f, 0.f, 0.f, 0.f);
        if (rowok) {
            if (AMODE == 3) {
                int z = kg >> 9, kk = kg & 511;
                const float* base = (z == 1) ? A2 : A;
                const float* src = base + (size_t)arow * 512 + kk;
                f0 = *(const float4*)src;
                f1 = *(const float4*)(src + 4);
                if (z >= 2) {
                    const float* mrow = (z == 2) ? A2 + (size_t)arow * 512 + kk
                                                 : q2nrow + kk;
                    float4 g0 = *(const float4*)mrow;
                    float4 g1 = *(const float4*)(mrow + 4);
                    f0 = make_float4(f0.x * g0.x, f0.y * g0.y, f0.z * g0.z, f0.w * g0.w);
                    f1 = make_float4(f1.x * g1.x, f1.y * g1.y, f1.z * g1.z, f1.w * g1.w);
                }
            } else {
                const float* src = A + (size_t)arow * lda + kg;
                if (kg + 8 <= Klim) {
                    f0 = *(const float4*)src;
                    f1 = *(const float4*)(src + 4);
                } else if (kg + 4 <= Klim) {
                    f0 = *(const float4*)src;
                }
            }
        }
    };

    const int ktot = K >> 6;
    if (AMODE == 1) {
        gld16(abase + ko0, As + wbase);
        gld16(abase + ko1, As + 2048 + wbase);
    } else {
        stageAF(ko0, raf0, raf1);
        stageAF(ko1, raf2, raf3);
        *(bf16x8_t*)(As + t * 8) = cvt8(raf0, raf1);
        *(bf16x8_t*)(As + 2048 + t * 8) = cvt8(raf2, raf3);
    }
    gld16(bbase + ko0, Bts + wbase);
    gld16(bbase + ko1, Bts + 2048 + wbase);

    for (int kt = 0; kt < ktot; ++kt) {
        __syncthreads();
        const int cur = (kt & 1) * 4096;
        const int nxt = cur ^ 4096;
        const bool more = (kt + 1) < ktot;
        const int kn = (kt + 1) << 6;
        if (more) {
            if (AMODE == 1) {
                gld16(abase + kn + ko0, As + nxt + wbase);
                gld16(abase + kn + ko1, As + nxt + 2048 + wbase);
            } else {
                stageAF(kn + ko0, raf0, raf1);
                stageAF(kn + ko1, raf2, raf3);
            }
            gld16(bbase + kn + ko0, Bts + nxt + wbase);
            gld16(bbase + kn + ko1, Bts + nxt + 2048 + wbase);
        }
        {
            bf16x8_t a0 = *(const bf16x8_t*)(As + cur + apo0);
            bf16x8_t a1 = *(const bf16x8_t*)(As + cur + apo1);
            bf16x8_t b0 = *(const bf16x8_t*)(Bts + cur + bpo0);
            bf16x8_t b1 = *(const bf16x8_t*)(Bts + cur + bpo1);
            acc[0][0] = __builtin_amdgcn_mfma_f32_16x16x32_bf16(a0, b0, acc[0][0], 0, 0, 0);
            acc[0][1] = __builtin_amdgcn_mfma_f32_16x16x32_bf16(a0, b1, acc[0][1], 0, 0, 0);
            acc[1][0] = __builtin_amdgcn_mfma_f32_16x16x32_bf16(a1, b0, acc[1][0], 0, 0, 0);
            acc[1][1] = __builtin_amdgcn_mfma_f32_16x16x32_bf16(a1, b1, acc[1][1], 0, 0, 0);
        }
        {
            bf16x8_t a0 = *(const bf16x8_t*)(As + cur + 2048 + apo0);
            bf16x8_t a1 = *(const bf16x8_t*)(As + cur + 2048 + apo1);
            bf16x8_t b0 = *(const bf16x8_t*)(Bts + cur + 2048 + bpo0);
            bf16x8_t b1 = *(const bf16x8_t*)(Bts + cur + 2048 + bpo1);
            acc[0][0] = __builtin_amdgcn_mfma_f32_16x16x32_bf16(a0, b0, acc[0][0], 0, 0, 0);
            acc[0][1] = __builtin_amdgcn_mfma_f32_16x16x32_bf16(a0, b1, acc[0][1], 0, 0, 0);
            acc[1][0] = __builtin_amdgcn_mfma_f32_16x16x32_bf16(a1, b0, acc[1][0], 0, 0, 0);
            acc[1][1] = __builtin_amdgcn_mfma_f32_16x16x32_bf16(a1, b1, acc[1][1], 0, 0, 0);
        }
        if (more && AMODE != 1) {
            *(bf16x8_t*)(As + nxt + t * 8) = cvt8(raf0, raf1);
            *(bf16x8_t*)(As + nxt + 2048 + t * 8) = cvt8(raf2, raf3);
        }
    }
}

#define EPI_SETUP                                         \
    int t = threadIdx.x, lane = t & 63, w = t >> 6;       \
    int wm = (w & 1) * 32, wn = (w >> 1) * 32;            \
    int quad = lane >> 4, cidx = lane & 15;               \
    (void)t; (void)lane; (void)wm; (void)wn; (void)quad; (void)cidx;

// R17: tile fully dead iff single-batch tile with i0 >= lens[b].
__device__ __forceinline__ bool tile_dead(int m0, const int* __restrict__ lens) {
    int bA = m0 / Nn;
    int lastRow = m0 + 63;
    if (lastRow >= Bn * Nn) lastRow = Bn * Nn - 1;
    int bB = lastRow / Nn;
    return (bA == bB) && ((m0 - bA * Nn) >= lens[bA]);
}

// ---------------------------------------------------------------------------
// R22 fused input dispatch, 1601 blocks 1D:
//   idx <  504: nc = tanh(ng@Wn+bn), lh0
//   idx <  536: qc = qg@Wq + bq
//   idx <  600: Whc2 = Wh @ Wc_hi  -> WhcT rows 1024-1535
//   idx == 600: bhc2 = bh @ Wc_hi
//   idx >= 601: neighbor-list compaction from Asum (wave per row, in-order)
__global__ __launch_bounds__(256) void gemm_in_k(
    const float* __restrict__ ng, const float* __restrict__ qg,
    const float* __restrict__ Wh, const float* __restrict__ Wc,
    const float* __restrict__ bh, const float* __restrict__ Asum,
    const unsigned short* __restrict__ WnT, const unsigned short* __restrict__ WqT,
    const unsigned short* __restrict__ WcHiT,
    const float* __restrict__ bn, const float* __restrict__ bq,
    const int* __restrict__ lens,
    float* __restrict__ nc, unsigned short* __restrict__ lh0,
    float* __restrict__ qc,
    unsigned short* __restrict__ WhcT, float* __restrict__ bhc2,
    int* __restrict__ nidx, float* __restrict__ nval, int* __restrict__ cnt) {
    int idx = blockIdx.x;
    if (idx >= 601) {  // neighbor-list build: 1000 blocks x 4 waves = 4000 rows
        int wv = threadIdx.x >> 6, lane = threadIdx.x & 63;
        int row = (idx - 601) * 4 + wv;
        const float* arow = Asum + (size_t)row * 512;
        int* ni = nidx + (size_t)row * NLCAP;
        float* nv = nval + (size_t)row * NLCAP;
        int base = 0;
#pragma unroll
        for (int c = 0; c < 8; ++c) {
            int j = c * 64 + lane;
            float val = arow[j];  // cols 500-511 are zero-padded
            unsigned long long m = __ballot(val != 0.0f);
            if (val != 0.0f) {
                int pos = base + (int)__popcll(m & ((1ull << lane) - 1ull));
                if (pos < NLCAP) { ni[pos] = j; nv[pos] = val; }
            }
            base += (int)__popcll(m);
        }
        if (base > NLCAP) base = NLCAP;
        int padded = (base + 3) & ~3;
        if (padded > NLCAP) padded = NLCAP & ~3;
        if (lane < padded - base) { ni[base + lane] = 0; nv[base + lane] = 0.0f; }
        if (lane == 0) cnt[row] = padded;
        return;
    }
    if (idx == 600) {  // bhc2
        int n = threadIdx.x;
        float s0 = 0.f, s1 = 0.f;
        for (int k = 0; k < 512; ++k) {
            float bv = bh[k];
            s0 = fmaf(bv, Wc[(size_t)k * 512 + n], s0);
            s1 = fmaf(bv, Wc[(size_t)k * 512 + n + 256], s1);
        }
        bhc2[n] = s0; bhc2[n + 256] = s1;
        return;
    }
    __shared__ __align__(16) unsigned short As[8192], Bts[8192];
    f32x4_t z = {0.f, 0.f, 0.f, 0.f};
    f32x4_t acc[2][2] = {{z, z}, {z, z}};
    if (idx >= 536) {  // Whc2 tile (8x8)
        int l = idx - 536;
        int m0 = (l >> 3) * 64, n0 = (l & 7) * 64;
        mfma_core<0>(Wh, nullptr, nullptr, nullptr, 512, 512, WcHiT, 512,
                     m0, n0, 512, 512, As, Bts, acc);
        EPI_SETUP
#pragma unroll
        for (int nj = 0; nj < 2; ++nj) {
            int col = n0 + wn + nj * 16 + cidx;
#pragma unroll
            for (int mi = 0; mi < 2; ++mi) {
#pragma unroll
                for (int r = 0; r < 4; ++r) {
                    int row = m0 + wm + mi * 16 + quad * 4 + r;
                    WhcT[(size_t)(1024 + col) * 512 + row] = f2bf(acc[mi][nj][r]);
                }
            }
        }
        return;
    }
    const bool isq = idx >= 504;
    int xt = isq ? (idx - 504) % 4 : idx % 63;
    int yt = isq ? (idx - 504) / 4 : idx / 63;
    int m0 = xt * 64, n0 = yt * 64;
    const float* A = isq ? qg : ng;
    const unsigned short* Bt = isq ? WqT : WnT;
    const int Mlim = isq ? Bn * Qn : Bn * Nn;
    mfma_core<0>(A, nullptr, nullptr, nullptr, DIN, DIN, Bt, 320,
                 m0, n0, 320, Mlim, As, Bts, acc);
    EPI_SETUP
#pragma unroll
    for (int nj = 0; nj < 2; ++nj) {
        int col = n0 + wn + nj * 16 + cidx;
        float bias = isq ? bq[col] : bn[col];
#pragma unroll
        for (int mi = 0; mi < 2; ++mi) {
#pragma unroll
            for (int r = 0; r < 4; ++r) {
                int row = m0 + wm + mi * 16 + quad * 4 + r;
                if (row < Mlim) {
                    float v = acc[mi][nj][r] + bias;
                    if (isq) {
                        qc[(size_t)row * ENC + col] = v;
                    } else {
                        float tv = tanhf(v);
                        int b = row / Nn, i = row - b * Nn;
                        float rm = (i < lens[b]) ? 1.0f : 0.0f;
                        nc[(size_t)row * ENC + col] = tv;
                        lh0[(size_t)row * ENC + col] = f2bf(tv * rm);
                    }
                }
            }
        }
    }
}

// ---------------------------------------------------------------------------
// R21 hop K1: lh @ [Wh | Wc_lo | Whc2]  (N=1536, K=512), grid (63, 24).
// cols 0-511    -> hm = bf16((v+bh)*rm)
// cols 512-1023 -> pa = v (fp32)
// cols 1024-1535-> Xh = bf16((v + bhc2)*rm)   [R22: bf16, halves gather bytes]
__global__ __launch_bounds__(256) void gemm_hop_k(
    const unsigned short* __restrict__ lh, const unsigned short* __restrict__ WhcT,
    const float* __restrict__ bh, const float* __restrict__ bhc2,
    const int* __restrict__ lens,
    unsigned short* __restrict__ hm, float* __restrict__ pa,
    unsigned short* __restrict__ Xh) {
    int m0 = blockIdx.x * 64, n0 = blockIdx.y * 64;   // n0 in [0,1536)
    if (tile_dead(m0, lens)) {
        int tt = threadIdx.x;
        int row = m0 + (tt >> 2);
        int cseg = (tt & 3) * 16;
        if (row < Bn * Nn) {
            bf16x8_t zz = {0, 0, 0, 0, 0, 0, 0, 0};
            if (n0 < 512) {
                *(bf16x8_t*)(hm + (size_t)row * ENC + n0 + cseg) = zz;
                *(bf16x8_t*)(hm + (size_t)row * ENC + n0 + cseg + 8) = zz;
            } else if (n0 >= 1024) {
                int c0 = (n0 - 1024) + cseg;
                *(bf16x8_t*)(Xh + (size_t)row * 512 + c0) = zz;
                *(bf16x8_t*)(Xh + (size_t)row * 512 + c0 + 8) = zz;
            }
        }
        return;
    }
    __shared__ __align__(16) unsigned short As[8192], Bts[8192];
    f32x4_t z = {0.f, 0.f, 0.f, 0.f};
    f32x4_t acc[2][2] = {{z, z}, {z, z}};
    mfma_core<1>(nullptr, nullptr, nullptr, lh, ENC, ENC, WhcT, 512, m0, n0, ENC,
                 Bn * Nn, As, Bts, acc);
    EPI_SETUP
#pragma unroll
    for (int nj = 0; nj < 2; ++nj) {
        int col = n0 + wn + nj * 16 + cidx;
#pragma unroll
        for (int mi = 0; mi < 2; ++mi) {
#pragma unroll
            for (int r = 0; r < 4; ++r) {
                int row = m0 + wm + mi * 16 + quad * 4 + r;
                if (row < Bn * Nn) {
                    int b = row / Nn, i = row - b * Nn;
                    float rm = (i < lens[b]) ? 1.0f : 0.0f;
                    float v = acc[mi][nj][r];
                    if (col < 512) {
                        hm[(size_t)row * ENC + col] = f2bf((v + bh[col]) * rm);
                    } else if (col < 1024) {
                        pa[(size_t)row * ENC + (col - 512)] = v;
                    } else {
                        Xh[(size_t)row * 512 + (col - 1024)] =
                            f2bf((v + bhc2[col - 1024]) * rm);
                    }
                }
            }
        }
    }
}

// ---------------------------------------------------------------------------
// R22 hop K2: list-driven dual gather + attention + hop update.
// Uses precomputed neighbor lists (no ballot/ffsll serial chain); loads for
// successive neighbors are independent -> deep pipelining.
__global__ __launch_bounds__(256) void upd_att_k(
    const int* __restrict__ nidx, const float* __restrict__ nval,
    const int* __restrict__ cnt,
    const unsigned short* __restrict__ hm, const unsigned short* __restrict__ Xh,
    const float* __restrict__ pa, const float* __restrict__ bc,
    const int* __restrict__ lens,
    const unsigned short* __restrict__ lh, unsigned short* __restrict__ lh_out) {
    int wv = threadIdx.x >> 6, lane = threadIdx.x & 63;
    int row = blockIdx.x * 4 + wv;
    int b = row / Nn, i = row - b * Nn;
    int d0 = lane * 8;
    if (i >= lens[b]) {
        bf16x8_t zz = {0, 0, 0, 0, 0, 0, 0, 0};
        *(bf16x8_t*)(lh_out + (size_t)row * ENC + d0) = zz;
        return;
    }
    const unsigned short* hmb = hm + (size_t)b * Nn * ENC;
    const unsigned short* Xhb = Xh + (size_t)b * Nn * 512;

    float ua[8], xa[8];
    {
        bf16x8_t h = *(const bf16x8_t*)(hmb + (size_t)i * ENC + d0);
        bf16x8_t x = *(const bf16x8_t*)(Xhb + (size_t)i * 512 + d0);
#pragma unroll
        for (int j = 0; j < 8; ++j) {
            ua[j] = bf2f((unsigned short)h[j]);
            xa[j] = bf2f((unsigned short)x[j]);
        }
    }
    const int* ni = nidx + (size_t)row * NLCAP;
    const float* nv = nval + (size_t)row * NLCAP;
    int cn = cnt[row];
    for (int e = 0; e < cn; e += 4) {
        int4 jj = *(const int4*)(ni + e);
        float4 vv = *(const float4*)(nv + e);
        bf16x8_t h0 = *(const bf16x8_t*)(hmb + (size_t)jj.x * ENC + d0);
        bf16x8_t h1 = *(const bf16x8_t*)(hmb + (size_t)jj.y * ENC + d0);
        bf16x8_t h2 = *(const bf16x8_t*)(hmb + (size_t)jj.z * ENC + d0);
        bf16x8_t h3 = *(const bf16x8_t*)(hmb + (size_t)jj.w * ENC + d0);
        bf16x8_t x0 = *(const bf16x8_t*)(Xhb + (size_t)jj.x * 512 + d0);
        bf16x8_t x1 = *(const bf16x8_t*)(Xhb + (size_t)jj.y * 512 + d0);
        bf16x8_t x2 = *(const bf16x8_t*)(Xhb + (size_t)jj.z * 512 + d0);
        bf16x8_t x3 = *(const bf16x8_t*)(Xhb + (size_t)jj.w * 512 + d0);
#pragma unroll
        for (int k = 0; k < 8; ++k) {
            ua[k] += vv.x * bf2f((unsigned short)h0[k]) + vv.y * bf2f((unsigned short)h1[k]) +
                     vv.z * bf2f((unsigned short)h2[k]) + vv.w * bf2f((unsigned short)h3[k]);
            xa[k] += vv.x * bf2f((unsigned short)x0[k]) + vv.y * bf2f((unsigned short)x1[k]) +
                     vv.z * bf2f((unsigned short)x2[k]) + vv.w * bf2f((unsigned short)x3[k]);
        }
    }
    const float* pp = pa + (size_t)row * ENC + d0;
    float4 p0 = *(const float4*)pp, p1 = *(const float4*)(pp + 4);
    float4 c0 = *(const float4*)(bc + d0), c1 = *(const float4*)(bc + d0 + 4);
    float pk[8] = {p0.x, p0.y, p0.z, p0.w, p1.x, p1.y, p1.z, p1.w};
    float ck[8] = {c0.x, c0.y, c0.z, c0.w, c1.x, c1.y, c1.z, c1.w};
    bf16x8_t lr = *(const bf16x8_t*)(lh + (size_t)row * ENC + d0);
    float o[8];
#pragma unroll
    for (int k = 0; k < 8; ++k) {
        float a = sigmoidf_(xa[k] + pk[k] + ck[k]);   // rm=1 (valid row)
        float l = bf2f((unsigned short)lr[k]);
        o[k] = a * tanhf(ua[k]) + (1.0f - a) * l;
    }
    float4 o0 = make_float4(o[0], o[1], o[2], o[3]);
    float4 o1 = make_float4(o[4], o[5], o[6], o[7]);
    *(bf16x8_t*)(lh_out + (size_t)row * ENC + d0) = cvt8(o0, o1);
}

// ---------------------------------------------------------------------------
// R22 merged final: g @ W1 (full K=2048 via AMODE 3, two 64-col passes) then
// raw[row] = b2 + sum_col tanh(v + b1)*W2 reduced in-block.  Grid: 63 blocks.
__global__ __launch_bounds__(256) void gemm_final2_k(
    const float* __restrict__ nc, const float* n2q,
    const float* __restrict__ q2n,
    const unsigned short* __restrict__ W1T,
    const float* __restrict__ b1p, const float* __restrict__ W2p,
    const float* __restrict__ b2p, float* __restrict__ raw) {
    __shared__ __align__(16) unsigned short As[8192], Bts[8192];
    __shared__ float red[64][2];
    constexpr int M = Bn * Nn;
    f32x4_t z4 = {0.f, 0.f, 0.f, 0.f};
    f32x4_t acc0[2][2] = {{z4, z4}, {z4, z4}};
    f32x4_t acc1[2][2] = {{z4, z4}, {z4, z4}};
    int m0 = blockIdx.x * 64;
    mfma_core<3>(nc, n2q, q2n, nullptr, 512, 1 << 30, W1T, 2048,
                 m0, 0, 2048, M, As, Bts, acc0);
    __syncthreads();
    mfma_core<3>(nc, n2q, q2n, nullptr, 512, 1 << 30, W1T, 2048,
                 m0, 64, 2048, M, As, Bts, acc1);
    EPI_SETUP
#pragma unroll
    for (int mi = 0; mi < 2; ++mi) {
#pragma unroll
        for (int r = 0; r < 4; ++r) {
            float s = 0.f;
#pragma unroll
            for (int nj = 0; nj < 2; ++nj) {
                int c0 = wn + nj * 16 + cidx;
                s += tanhf(acc0[mi][nj][r] + b1p[c0]) * W2p[c0];
                s += tanhf(acc1[mi][nj][r] + b1p[c0 + 64]) * W2p[c0 + 64];
            }
            s += __shfl_xor(s, 1, 64);
            s += __shfl_xor(s, 2, 64);
            s += __shfl_xor(s, 4, 64);
            s += __shfl_xor(s, 8, 64);
            if (cidx == 0) red[wm + mi * 16 + quad * 4 + r][w >> 1] = s;
        }
    }
    __syncthreads();
    if (t < 64) {
        int row = m0 + t;
        if (row < M) raw[row] = red[t][0] + red[t][1] + b2p[0];
    }
}

// ---------------------------------------------------------------------------
// Fused sim -> softmax(q) -> nodes2query + rowmax.  One wave per n-row.
__global__ __launch_bounds__(256) void sim_fused_k(const unsigned short* __restrict__ lh,
                                                   const float* __restrict__ qc,
                                                   const float* __restrict__ wa,
                                                   const int* __restrict__ lens,
                                                   float* __restrict__ n2q,
                                                   float* __restrict__ rowmax) {
    __shared__ float qcs[Qn * ENC];
    __shared__ float qdot[32];
    int b = blockIdx.x;
    int t = threadIdx.x;
    const float* qcb = qc + (size_t)b * Qn * ENC;
    for (int i = t * 4; i < Qn * ENC; i += 1024) *(float4*)&qcs[i] = *(const float4*)&qcb[i];
    __syncthreads();
    {
        int q = t >> 3, j = t & 7;
        if (q < Qn) {
            float s = 0.f;
            for (int k = 0; k < 64; ++k) {
                int d = j + 8 * k;
                s += qcs[q * ENC + d] * wa[ENC + d];
            }
            s += __shfl_xor(s, 1, 64);
            s += __shfl_xor(s, 2, 64);
            s += __shfl_xor(s, 4, 64);
            if (j == 0) qdot[q] = s;
        }
    }
    __syncthreads();

    int wv = t >> 6, lane = t & 63;
    int n = blockIdx.y * 4 + wv;
    int dA = lane * 4;
    int dB = 256 + lane * 4;
    const bool valid = n < lens[b];

    float s_[Qn];
    if (valid) {
        const unsigned short* lrow = lh + ((size_t)b * Nn + n) * ENC;
        ushort4 ua = *(const ushort4*)(lrow + dA);
        ushort4 ub = *(const ushort4*)(lrow + dB);
        float lv[8] = {bf2f(ua.x), bf2f(ua.y), bf2f(ua.z), bf2f(ua.w),
                       bf2f(ub.x), bf2f(ub.y), bf2f(ub.z), bf2f(ub.w)};
        float ndp = 0.f;
        float lvs[8];
#pragma unroll
        for (int j = 0; j < 4; ++j) {
            ndp += lv[j] * wa[dA + j];
            lvs[j] = lv[j] * wa[2 * ENC + dA + j];
            ndp += lv[4 + j] * wa[dB + j];
            lvs[4 + j] = lv[4 + j] * wa[2 * ENC + dB + j];
        }
#pragma unroll
        for (int off = 32; off; off >>= 1) ndp += __shfl_xor(ndp, off, 64);

#pragma unroll
        for (int q = 0; q < Qn; ++q) {
            float4 qa = *(const float4*)(qcs + q * ENC + dA);
            float4 qb = *(const float4*)(qcs + q * ENC + dB);
            s_[q] = lvs[0] * qa.x + lvs[1] * qa.y + lvs[2] * qa.z + lvs[3] * qa.w +
                    lvs[4] * qb.x + lvs[5] * qb.y + lvs[6] * qb.z + lvs[7] * qb.w;
        }
#pragma unroll
        for (int q = 0; q < Qn; ++q) {
#pragma unroll
            for (int off = 32; off; off >>= 1) s_[q] += __shfl_xor(s_[q], off, 64);
        }
#pragma unroll
        for (int q = 0; q < Qn; ++q) s_[q] += ndp + qdot[q];
    } else {
#pragma unroll
        for (int q = 0; q < Qn; ++q) s_[q] = qdot[q];
    }

    float mx = -INFINITY;
#pragma unroll
    for (int q = 0; q < Qn; ++q) mx = fmaxf(mx, s_[q]);
    float sum = 0.f;
#pragma unroll
    for (int q = 0; q < Qn; ++q) { s_[q] = expf(s_[q] - mx); sum += s_[q]; }
    float inv = 1.0f / sum;
    float o[8] = {};
#pragma unroll
    for (int q = 0; q < Qn; ++q) {
        float4 qa = *(const float4*)(qcs + q * ENC + dA);
        float4 qb = *(const float4*)(qcs + q * ENC + dB);
        float p = s_[q] * inv;
        o[0] += p * qa.x; o[1] += p * qa.y; o[2] += p * qa.z; o[3] += p * qa.w;
        o[4] += p * qb.x; o[5] += p * qb.y; o[6] += p * qb.z; o[7] += p * qb.w;
    }
    float* orow = n2q + ((size_t)b * Nn + n) * ENC;
    *(float4*)(orow + dA) = make_float4(o[0], o[1], o[2], o[3]);
    *(float4*)(orow + dB) = make_float4(o[4], o[5], o[6], o[7]);
    if (lane == 0) rowmax[b * Nn + n] = mx;
}

// ---------------------------------------------------------------------------
// Fused bvec (softmax over rowmax) + q2n (bvec-weighted sum of nc).
__global__ __launch_bounds__(512) void bvec_q2n_k(const float* __restrict__ rowmax,
                                                  const float* __restrict__ nc,
                                                  float* __restrict__ q2n) {
    __shared__ float red[8];
    __shared__ float bvs[512];
    int b = blockIdx.x, t = threadIdx.x;
    float v = (t < Nn) ? rowmax[b * Nn + t] : -INFINITY;
    float m = v;
    for (int off = 32; off; off >>= 1) m = fmaxf(m, __shfl_xor(m, off, 64));
    if ((t & 63) == 0) red[t >> 6] = m;
    __syncthreads();
    float bm = red[0];
    for (int i = 1; i < 8; ++i) bm = fmaxf(bm, red[i]);
    float e = (t < Nn) ? expf(v - bm) : 0.0f;
    float ssum = e;
    for (int off = 32; off; off >>= 1) ssum += __shfl_xor(ssum, off, 64);
    __syncthreads();
    if ((t & 63) == 0) red[t >> 6] = ssum;
    __syncthreads();
    float tot = 0.f;
    for (int i = 0; i < 8; ++i) tot += red[i];
    bvs[t] = e / tot;
    __syncthreads();
    const float* ncb = nc + (size_t)b * Nn * ENC;
    float acc = 0.f;
    for (int n = 0; n < Nn; ++n) acc = fmaf(bvs[n], ncb[(size_t)n * ENC + t], acc);
    q2n[b * ENC + t] = acc;
}

// ---------------------------------------------------------------------------
__global__ __launch_bounds__(256) void predmax_k(const int* __restrict__ mask,
                                                 const float* __restrict__ raw,
                                                 float* __restrict__ out) {
    int idx = blockIdx.x * 4 + (threadIdx.x >> 6);
    int lane = threadIdx.x & 63;
    if (idx >= Bn * NCn) return;
    int b = idx / NCn, c = idx - b * NCn;
    const int* mrow = mask + ((size_t)b * NCn + c) * Nn;
    const float* rrow = raw + (size_t)b * Nn;
    float mx = -INFINITY;
    for (int n = lane; n < Nn; n += 64) {
        float v = mrow[n] ? rrow[n] : 0.0f;
        if (v == 0.0f) v = -1.0e6f;
        mx = fmaxf(mx, v);
    }
    for (int off = 32; off; off >>= 1) mx = fmaxf(mx, __shfl_xor(mx, off, 64));
    if (lane == 0) out[idx] = mx;
}

}  // namespace

extern "C" void kernel_launch(void* const* d_in, const int* in_sizes, int n_in,
                              void* d_out, int out_size, void* d_ws, size_t ws_size,
                              hipStream_t stream) {
    const float* nodes_glove  = (const float*)d_in[0];
    const float* query_glove  = (const float*)d_in[1];
    const float* adj          = (const float*)d_in[2];
    const int*   nodes_length = (const int*)d_in[3];
    const int*   maskp        = (const int*)d_in[4];
    const float* Wn = (const float*)d_in[5];
    const float* bn = (const float*)d_in[6];
    const float* Wq = (const float*)d_in[7];
    const float* bq = (const float*)d_in[8];
    const float* Wh = (const float*)d_in[9];
    const float* bh = (const float*)d_in[10];
    const float* Wc = (const float*)d_in[11];
    const float* bc = (const float*)d_in[12];
    const float* wa = (const float*)d_in[13];
    const float* W1 = (const float*)d_in[14];
    const float* b1 = (const float*)d_in[15];
    const float* W2 = (const float*)d_in[16];
    const float* b2 = (const float*)d_in[17];
    float* out = (float*)d_out;

    float* ws = (float*)d_ws;
    size_t off = 0;
    auto alloc = [&](size_t n) { float* p = ws + off; off += n; return p; };
    constexpr size_t ME  = (size_t)Bn * Nn * ENC;       // 2,048,000 fp32 elems
    constexpr size_t MEH = ME / 2;
    float* nc   = alloc(ME);
    float* Asum = alloc(ME);       // fp32 adjacency; aliased as n2q after hops
    float* pa   = alloc(ME);       // fp32 partial att logits (lh @ Wc_lo)
    unsigned short* lh0 = (unsigned short*)alloc(MEH);
    unsigned short* lh1 = (unsigned short*)alloc(MEH);
    unsigned short* hm  = (unsigned short*)alloc(MEH);
    unsigned short* Xh  = (unsigned short*)alloc(MEH);  // bf16 X (R22)
    float* qc   = alloc((size_t)Bn * Qn * ENC);
    float* rowmax = alloc(Bn * Nn);
    float* q2n    = alloc(Bn * ENC);
    float* raw    = alloc(Bn * Nn);
    float* bhc2   = alloc(512);
    int*   nidx = (int*)alloc((size_t)Bn * Nn * NLCAP);   // R22 neighbor lists
    float* nval = alloc((size_t)Bn * Nn * NLCAP);
    int*   cntp = (int*)alloc(Bn * Nn);
    unsigned short* WnT  = (unsigned short*)alloc((size_t)ENC * 320 / 2);
    unsigned short* WqT  = (unsigned short*)alloc((size_t)ENC * 320 / 2);
    unsigned short* WhcT = (unsigned short*)alloc((size_t)1536 * 512 / 2);
    unsigned short* WcHiT = (unsigned short*)alloc((size_t)512 * 512 / 2);
    unsigned short* W1T  = (unsigned short*)alloc((size_t)128 * 2048 / 2);
    alloc(16384);  // tail pad
    float* n2q = Asum;             // after hops

    constexpr int M = Bn * Nn;  // 4000

    // 1. Fused prep: Asum (z=1) + weight transposes (z=0).
    prep_k<<<dim3(2048, 1, 2), 256, 0, stream>>>(adj, Asum, Wn, Wq, Wh, Wc, W1,
                                                 WnT, WqT, WhcT, WcHiT, W1T);

    // 2. Fused input GEMMs + Whc2 + bhc2 + neighbor lists (1601 blocks).
    gemm_in_k<<<dim3(1601), 256, 0, stream>>>(nodes_glove, query_glove, Wh, Wc, bh,
                                              Asum, WnT, WqT, WcHiT, bn, bq,
                                              nodes_length, nc, lh0, qc, WhcT, bhc2,
                                              nidx, nval, cntp);

    // 3-8. 3 hops x 2 dispatches.
    unsigned short* cur = lh0;
    unsigned short* nxt = lh1;
    for (int h = 0; h < 3; ++h) {
        gemm_hop_k<<<dim3(63, 24), 256, 0, stream>>>(cur, WhcT, bh, bhc2,
                                                     nodes_length, hm, pa, Xh);
        upd_att_k<<<dim3(M / 4), 256, 0, stream>>>(nidx, nval, cntp, hm, Xh, pa, bc,
                                                   nodes_length, cur, nxt);
        unsigned short* tmp = cur; cur = nxt; nxt = tmp;
    }
    // cur == lh1 == final last_hop.

    // 9-12. Tail (final GEMM + reduce merged).
    sim_fused_k<<<dim3(Bn, 125), 256, 0, stream>>>(cur, qc, wa, nodes_length, n2q, rowmax);
    bvec_q2n_k<<<dim3(Bn), 512, 0, stream>>>(rowmax, nc, q2n);
    gemm_final2_k<<<dim3((M + 63) / 64), 256, 0, stream>>>(nc, n2q, q2n, W1T,
                                                           b1, W2, b2, raw);
    predmax_k<<<dim3((Bn * NCn + 3) / 4), 256, 0, stream>>>(maskp, raw, out);
}

// Round 9
// 297.798 us; speedup vs baseline: 1.1523x; 1.1523x over previous
//
#include <hip/hip_runtime.h>
#include <hip/hip_bf16.h>
#include <math.h>
#include <stdint.h>

namespace {

constexpr int Bn  = 8;
constexpr int Nn  = 500;
constexpr int Qn  = 25;
constexpr int ENC = 512;
constexpr int DIN = 300;
constexpr int NCn = 70;
constexpr int NETn = 3;
constexpr int NLCAP = 96;   // neighbor-list capacity (mean 29.4, sigma 5.3 -> 12.7 sigma)

typedef __attribute__((ext_vector_type(8))) short bf16x8_t;
typedef __attribute__((ext_vector_type(4))) float f32x4_t;

__device__ __forceinline__ unsigned short f2bf(float f) {
    union { __hip_bfloat16 b; unsigned short u; } r;
    r.b = __float2bfloat16(f);
    return r.u;
}
__device__ __forceinline__ bf16x8_t cvt8(float4 f0, float4 f1) {
    union { bf16x8_t v; __hip_bfloat162 b[4]; } r;
    r.b[0] = __float22bfloat162_rn(make_float2(f0.x, f0.y));
    r.b[1] = __float22bfloat162_rn(make_float2(f0.z, f0.w));
    r.b[2] = __float22bfloat162_rn(make_float2(f1.x, f1.y));
    r.b[3] = __float22bfloat162_rn(make_float2(f1.z, f1.w));
    return r.v;
}
__device__ __forceinline__ float bf2f(unsigned short h) {
    unsigned int u = ((unsigned int)h) << 16;
    return __builtin_bit_cast(float, u);
}
__device__ __forceinline__ float sigmoidf_(float x) { return 1.0f / (1.0f + expf(-x)); }

// R20: async global->LDS, 16B per lane (dest = wave-uniform base + lane*16B).
typedef __attribute__((address_space(1))) const unsigned int g_u32;
typedef __attribute__((address_space(3))) unsigned int l_u32;
__device__ __forceinline__ void gld16(const void* g, void* l) {
    __builtin_amdgcn_global_load_lds((g_u32*)g, (l_u32*)l, 16, 0, 0);
}

// ---------------------------------------------------------------------------
// Fused prep: z=1 -> Asum; z=0 -> weight transposes.
__global__ __launch_bounds__(256) void prep_k(
    const float* __restrict__ adj, float* __restrict__ Asum,
    const float* __restrict__ Wn, const float* __restrict__ Wq,
    const float* __restrict__ Wh, const float* __restrict__ Wc,
    const float* __restrict__ W1,
    unsigned short* __restrict__ WnT, unsigned short* __restrict__ WqT,
    unsigned short* __restrict__ WhcT, unsigned short* __restrict__ WcHiT,
    unsigned short* __restrict__ W1T) {
    if (blockIdx.z == 1) {
        int bi = blockIdx.x * 2 + (threadIdx.x >> 7);
        if (bi >= Bn * Nn) return;
        int b = bi / Nn, i = bi - b * Nn;
        int j = (threadIdx.x & 127) * 4;
        float4 s = make_float4(0.f, 0.f, 0.f, 0.f);
        if (j < Nn) {
#pragma unroll
            for (int e = 0; e < NETn; ++e) {
                const float* p = adj + (((size_t)(b * NETn + e) * Nn) + i) * Nn + j;
                float4 v = *(const float4*)p;
                s.x += v.x; s.y += v.y; s.z += v.z; s.w += v.w;
            }
        }
        *(float4*)(Asum + ((size_t)bi) * 512 + j) = s;
        return;
    }
    __shared__ float tile[32][33];
    int x = blockIdx.x;
    const float* in; unsigned short* out; int K, N, Kpad, tx, ty;
    if (x < 160)       { in = Wn; out = WnT; K = DIN; N = ENC; Kpad = 320;
                         tx = x & 15; ty = x >> 4; }
    else if (x < 320)  { int l = x - 160; in = Wq; out = WqT; K = DIN; N = ENC;
                         Kpad = 320; tx = l & 15; ty = l >> 4; }
    else if (x < 576)  { int l = x - 320; in = Wh; out = WhcT; K = 512; N = ENC;
                         Kpad = 512; tx = l & 15; ty = l >> 4; }
    else if (x < 832)  { int l = x - 576; in = Wc + (size_t)512 * ENC;
                         out = WhcT + (size_t)512 * 512; K = 512; N = ENC;
                         Kpad = 512; tx = l & 15; ty = l >> 4; }
    else if (x < 1088) { int l = x - 832; in = Wc; out = WcHiT; K = 512; N = ENC;
                         Kpad = 512; tx = l & 15; ty = l >> 4; }
    else if (x < 1344) { int l = x - 1088; in = W1; out = W1T; K = 2048; N = 128;
                         Kpad = 2048; tx = l & 3; ty = l >> 2; }
    else return;
    int n0 = tx * 32, k0 = ty * 32;
    int ltx = threadIdx.x & 31, lty = threadIdx.x >> 5;
#pragma unroll
    for (int r = 0; r < 4; ++r) {
        int k = k0 + lty * 4 + r;
        int n = n0 + ltx;
        tile[lty * 4 + r][ltx] = (k < K && n < N) ? in[(size_t)k * N + n] : 0.0f;
    }
    __syncthreads();
#pragma unroll
    for (int r = 0; r < 4; ++r) {
        int n = n0 + lty * 4 + r;
        int k = k0 + ltx;
        if (n < N && k < Kpad) out[(size_t)n * Kpad + k] = f2bf(tile[ltx][lty * 4 + r]);
    }
}

// ---------------------------------------------------------------------------
// MFMA core, BK=64: 64x64 tile, 4 waves, double-buffered LDS.
// AMODE 0: A fp32 (Klim clamp).  AMODE 1: A bf16 (gld16 direct).
// AMODE 2: A = fp32 product stage — a2mode 0: A only; 1: A*A2 same-row;
// 2: A * A2[b-row broadcast].  B always bf16 B^T via gld16.
template <int AMODE>
__device__ __forceinline__ void mfma_core(
    const float* __restrict__ A, const float* __restrict__ A2, int a2mode,
    const unsigned short* __restrict__ Abf,
    int lda, int Klim,
    const unsigned short* __restrict__ Bt, int ldb,
    int m0, int n0, int K, int Mlim,
    unsigned short* As, unsigned short* Bts, f32x4_t acc[2][2]) {
    const int t = threadIdx.x;
    const int lane = t & 63;
    const int w = t >> 6;
    const int sm = t >> 2;
    const int sp = t & 3;
    const int sq = sp ^ ((sm >> 1) & 3);
    const int arow = m0 + sm;
    const bool rowok = arow < Mlim;
    const int arowc = rowok ? arow : (Mlim - 1);
    const int wm = (w & 1) * 32, wn = (w >> 1) * 32;
    const int quad = lane >> 4, cidx = lane & 15;
    const int am0 = wm + cidx, am1 = wm + 16 + cidx;
    const int an0 = wn + cidx, an1 = wn + 16 + cidx;
    const int apo0 = am0 * 32 + (quad ^ ((am0 >> 1) & 3)) * 8;
    const int apo1 = am1 * 32 + (quad ^ ((am1 >> 1) & 3)) * 8;
    const int bpo0 = an0 * 32 + (quad ^ ((an0 >> 1) & 3)) * 8;
    const int bpo1 = an1 * 32 + (quad ^ ((an1 >> 1) & 3)) * 8;
    const int wbase = w * 512;  // shorts; wave-uniform LDS base

    const unsigned short* abase = (AMODE == 1) ? Abf + (size_t)arowc * lda : nullptr;
    const unsigned short* bbase = Bt + (size_t)(n0 + sm) * ldb;
    const int ko0 = sq * 8, ko1 = 32 + sq * 8;
    const float* a2row = nullptr;
    if (AMODE == 2 && A2 != nullptr)
        a2row = (a2mode == 2) ? A2 + (size_t)(arowc / Nn) * ENC
                              : A2 + (size_t)arowc * lda;

    float4 raf0, raf1, raf2, raf3;  // fp32 A reg staging
    auto stageAF = [&](int kg, float4& f0, float4& f1) {
        f0 = make_float4(0.f, 0.f, 0.f, 0.f);
        f1 = make_float4(0.f, 0.f, 0.f, 0.f);
        if (rowok) {
            const float* src = A + (size_t)arow * lda + kg;
            if (AMODE == 2) {
                f0 = *(const float4*)src;
                f1 = *(const float4*)(src + 4);
                if (a2mode) {
                    float4 g0 = *(const float4*)(a2row + kg);
                    float4 g1 = *(const float4*)(a2row + kg + 4);
                    f0 = make_float4(f0.x * g0.x, f0.y * g0.y, f0.z * g0.z, f0.w * g0.w);
                    f1 = make_float4(f1.x * g1.x, f1.y * g1.y, f1.z * g1.z, f1.w * g1.w);
                }
            } else {
                if (kg + 8 <= Klim) {
                    f0 = *(const float4*)src;
                    f1 = *(const float4*)(src + 4);
                } else if (kg + 4 <= Klim) {
                    f0 = *(const float4*)src;
                }
            }
        }
    };

    const int ktot = K >> 6;
    if (AMODE == 1) {
        gld16(abase + ko0, As + wbase);
        gld16(abase + ko1, As + 2048 + wbase);
    } else {
        stageAF(ko0, raf0, raf1);
        stageAF(ko1, raf2, raf3);
        *(bf16x8_t*)(As + t * 8) = cvt8(raf0, raf1);
        *(bf16x8_t*)(As + 2048 + t * 8) = cvt8(raf2, raf3);
    }
    gld16(bbase + ko0, Bts + wbase);
    gld16(bbase + ko1, Bts + 2048 + wbase);

    for (int kt = 0; kt < ktot; ++kt) {
        __syncthreads();
        const int cur = (kt & 1) * 4096;
        const int nxt = cur ^ 4096;
        const bool more = (kt + 1) < ktot;
        const int kn = (kt + 1) << 6;
        if (more) {
            if (AMODE == 1) {
                gld16(abase + kn + ko0, As + nxt + wbase);
                gld16(abase + kn + ko1, As + nxt + 2048 + wbase);
            } else {
                stageAF(kn + ko0, raf0, raf1);
                stageAF(kn + ko1, raf2, raf3);
            }
            gld16(bbase + kn + ko0, Bts + nxt + wbase);
            gld16(bbase + kn + ko1, Bts + nxt + 2048 + wbase);
        }
        {
            bf16x8_t a0 = *(const bf16x8_t*)(As + cur + apo0);
            bf16x8_t a1 = *(const bf16x8_t*)(As + cur + apo1);
            bf16x8_t b0 = *(const bf16x8_t*)(Bts + cur + bpo0);
            bf16x8_t b1 = *(const bf16x8_t*)(Bts + cur + bpo1);
            acc[0][0] = __builtin_amdgcn_mfma_f32_16x16x32_bf16(a0, b0, acc[0][0], 0, 0, 0);
            acc[0][1] = __builtin_amdgcn_mfma_f32_16x16x32_bf16(a0, b1, acc[0][1], 0, 0, 0);
            acc[1][0] = __builtin_amdgcn_mfma_f32_16x16x32_bf16(a1, b0, acc[1][0], 0, 0, 0);
            acc[1][1] = __builtin_amdgcn_mfma_f32_16x16x32_bf16(a1, b1, acc[1][1], 0, 0, 0);
        }
        {
            bf16x8_t a0 = *(const bf16x8_t*)(As + cur + 2048 + apo0);
            bf16x8_t a1 = *(const bf16x8_t*)(As + cur + 2048 + apo1);
            bf16x8_t b0 = *(const bf16x8_t*)(Bts + cur + 2048 + bpo0);
            bf16x8_t b1 = *(const bf16x8_t*)(Bts + cur + 2048 + bpo1);
            acc[0][0] = __builtin_amdgcn_mfma_f32_16x16x32_bf16(a0, b0, acc[0][0], 0, 0, 0);
            acc[0][1] = __builtin_amdgcn_mfma_f32_16x16x32_bf16(a0, b1, acc[0][1], 0, 0, 0);
            acc[1][0] = __builtin_amdgcn_mfma_f32_16x16x32_bf16(a1, b0, acc[1][0], 0, 0, 0);
            acc[1][1] = __builtin_amdgcn_mfma_f32_16x16x32_bf16(a1, b1, acc[1][1], 0, 0, 0);
        }
        if (more && AMODE != 1) {
            *(bf16x8_t*)(As + nxt + t * 8) = cvt8(raf0, raf1);
            *(bf16x8_t*)(As + nxt + 2048 + t * 8) = cvt8(raf2, raf3);
        }
    }
}

#define EPI_SETUP                                         \
    int t = threadIdx.x, lane = t & 63, w = t >> 6;       \
    int wm = (w & 1) * 32, wn = (w >> 1) * 32;            \
    int quad = lane >> 4, cidx = lane & 15;               \
    (void)t; (void)lane; (void)wm; (void)wn; (void)quad; (void)cidx;

// R17: tile fully dead iff single-batch tile with i0 >= lens[b].
__device__ __forceinline__ bool tile_dead(int m0, const int* __restrict__ lens) {
    int bA = m0 / Nn;
    int lastRow = m0 + 63;
    if (lastRow >= Bn * Nn) lastRow = Bn * Nn - 1;
    int bB = lastRow / Nn;
    return (bA == bB) && ((m0 - bA * Nn) >= lens[bA]);
}

// ---------------------------------------------------------------------------
// R22 fused input dispatch, 1601 blocks 1D:
//   idx <  504: nc = tanh(ng@Wn+bn), lh0
//   idx <  536: qc = qg@Wq + bq
//   idx <  600: Whc2 = Wh @ Wc_hi  -> WhcT rows 1024-1535
//   idx == 600: bhc2 = bh @ Wc_hi
//   idx >= 601: neighbor-list compaction from Asum (wave per row, in-order)
__global__ __launch_bounds__(256) void gemm_in_k(
    const float* __restrict__ ng, const float* __restrict__ qg,
    const float* __restrict__ Wh, const float* __restrict__ Wc,
    const float* __restrict__ bh, const float* __restrict__ Asum,
    const unsigned short* __restrict__ WnT, const unsigned short* __restrict__ WqT,
    const unsigned short* __restrict__ WcHiT,
    const float* __restrict__ bn, const float* __restrict__ bq,
    const int* __restrict__ lens,
    float* __restrict__ nc, unsigned short* __restrict__ lh0,
    float* __restrict__ qc,
    unsigned short* __restrict__ WhcT, float* __restrict__ bhc2,
    int* __restrict__ nidx, float* __restrict__ nval, int* __restrict__ cnt) {
    int idx = blockIdx.x;
    if (idx >= 601) {  // neighbor-list build: 1000 blocks x 4 waves = 4000 rows
        int wv = threadIdx.x >> 6, lane = threadIdx.x & 63;
        int row = (idx - 601) * 4 + wv;
        const float* arow = Asum + (size_t)row * 512;
        int* ni = nidx + (size_t)row * NLCAP;
        float* nv = nval + (size_t)row * NLCAP;
        int base = 0;
#pragma unroll
        for (int c = 0; c < 8; ++c) {
            int j = c * 64 + lane;
            float val = arow[j];  // cols 500-511 are zero-padded
            unsigned long long m = __ballot(val != 0.0f);
            if (val != 0.0f) {
                int pos = base + (int)__popcll(m & ((1ull << lane) - 1ull));
                if (pos < NLCAP) { ni[pos] = j; nv[pos] = val; }
            }
            base += (int)__popcll(m);
        }
        if (base > NLCAP) base = NLCAP;
        int padded = (base + 3) & ~3;
        if (padded > NLCAP) padded = NLCAP & ~3;
        if (lane < padded - base) { ni[base + lane] = 0; nv[base + lane] = 0.0f; }
        if (lane == 0) cnt[row] = padded;
        return;
    }
    if (idx == 600) {  // bhc2
        int n = threadIdx.x;
        float s0 = 0.f, s1 = 0.f;
        for (int k = 0; k < 512; ++k) {
            float bv = bh[k];
            s0 = fmaf(bv, Wc[(size_t)k * 512 + n], s0);
            s1 = fmaf(bv, Wc[(size_t)k * 512 + n + 256], s1);
        }
        bhc2[n] = s0; bhc2[n + 256] = s1;
        return;
    }
    __shared__ __align__(16) unsigned short As[8192], Bts[8192];
    f32x4_t z = {0.f, 0.f, 0.f, 0.f};
    f32x4_t acc[2][2] = {{z, z}, {z, z}};
    if (idx >= 536) {  // Whc2 tile (8x8)
        int l = idx - 536;
        int m0 = (l >> 3) * 64, n0 = (l & 7) * 64;
        mfma_core<0>(Wh, nullptr, 0, nullptr, 512, 512, WcHiT, 512,
                     m0, n0, 512, 512, As, Bts, acc);
        EPI_SETUP
#pragma unroll
        for (int nj = 0; nj < 2; ++nj) {
            int col = n0 + wn + nj * 16 + cidx;
#pragma unroll
            for (int mi = 0; mi < 2; ++mi) {
#pragma unroll
                for (int r = 0; r < 4; ++r) {
                    int row = m0 + wm + mi * 16 + quad * 4 + r;
                    WhcT[(size_t)(1024 + col) * 512 + row] = f2bf(acc[mi][nj][r]);
                }
            }
        }
        return;
    }
    const bool isq = idx >= 504;
    int xt = isq ? (idx - 504) % 4 : idx % 63;
    int yt = isq ? (idx - 504) / 4 : idx / 63;
    int m0 = xt * 64, n0 = yt * 64;
    const float* A = isq ? qg : ng;
    const unsigned short* Bt = isq ? WqT : WnT;
    const int Mlim = isq ? Bn * Qn : Bn * Nn;
    mfma_core<0>(A, nullptr, 0, nullptr, DIN, DIN, Bt, 320,
                 m0, n0, 320, Mlim, As, Bts, acc);
    EPI_SETUP
#pragma unroll
    for (int nj = 0; nj < 2; ++nj) {
        int col = n0 + wn + nj * 16 + cidx;
        float bias = isq ? bq[col] : bn[col];
#pragma unroll
        for (int mi = 0; mi < 2; ++mi) {
#pragma unroll
            for (int r = 0; r < 4; ++r) {
                int row = m0 + wm + mi * 16 + quad * 4 + r;
                if (row < Mlim) {
                    float v = acc[mi][nj][r] + bias;
                    if (isq) {
                        qc[(size_t)row * ENC + col] = v;
                    } else {
                        float tv = tanhf(v);
                        int b = row / Nn, i = row - b * Nn;
                        float rm = (i < lens[b]) ? 1.0f : 0.0f;
                        nc[(size_t)row * ENC + col] = tv;
                        lh0[(size_t)row * ENC + col] = f2bf(tv * rm);
                    }
                }
            }
        }
    }
}

// ---------------------------------------------------------------------------
// R21 hop K1: lh @ [Wh | Wc_lo | Whc2]  (N=1536, K=512), grid (63, 24).
// cols 0-511    -> hm = bf16((v+bh)*rm)
// cols 512-1023 -> pa = v (fp32)
// cols 1024-1535-> Xh = bf16((v + bhc2)*rm)
__global__ __launch_bounds__(256) void gemm_hop_k(
    const unsigned short* __restrict__ lh, const unsigned short* __restrict__ WhcT,
    const float* __restrict__ bh, const float* __restrict__ bhc2,
    const int* __restrict__ lens,
    unsigned short* __restrict__ hm, float* __restrict__ pa,
    unsigned short* __restrict__ Xh) {
    int m0 = blockIdx.x * 64, n0 = blockIdx.y * 64;   // n0 in [0,1536)
    if (tile_dead(m0, lens)) {
        int tt = threadIdx.x;
        int row = m0 + (tt >> 2);
        int cseg = (tt & 3) * 16;
        if (row < Bn * Nn) {
            bf16x8_t zz = {0, 0, 0, 0, 0, 0, 0, 0};
            if (n0 < 512) {
                *(bf16x8_t*)(hm + (size_t)row * ENC + n0 + cseg) = zz;
                *(bf16x8_t*)(hm + (size_t)row * ENC + n0 + cseg + 8) = zz;
            } else if (n0 >= 1024) {
                int c0 = (n0 - 1024) + cseg;
                *(bf16x8_t*)(Xh + (size_t)row * 512 + c0) = zz;
                *(bf16x8_t*)(Xh + (size_t)row * 512 + c0 + 8) = zz;
            }
        }
        return;
    }
    __shared__ __align__(16) unsigned short As[8192], Bts[8192];
    f32x4_t z = {0.f, 0.f, 0.f, 0.f};
    f32x4_t acc[2][2] = {{z, z}, {z, z}};
    mfma_core<1>(nullptr, nullptr, 0, lh, ENC, ENC, WhcT, 512, m0, n0, ENC,
                 Bn * Nn, As, Bts, acc);
    EPI_SETUP
#pragma unroll
    for (int nj = 0; nj < 2; ++nj) {
        int col = n0 + wn + nj * 16 + cidx;
#pragma unroll
        for (int mi = 0; mi < 2; ++mi) {
#pragma unroll
            for (int r = 0; r < 4; ++r) {
                int row = m0 + wm + mi * 16 + quad * 4 + r;
                if (row < Bn * Nn) {
                    int b = row / Nn, i = row - b * Nn;
                    float rm = (i < lens[b]) ? 1.0f : 0.0f;
                    float v = acc[mi][nj][r];
                    if (col < 512) {
                        hm[(size_t)row * ENC + col] = f2bf((v + bh[col]) * rm);
                    } else if (col < 1024) {
                        pa[(size_t)row * ENC + (col - 512)] = v;
                    } else {
                        Xh[(size_t)row * 512 + (col - 1024)] =
                            f2bf((v + bhc2[col - 1024]) * rm);
                    }
                }
            }
        }
    }
}

// ---------------------------------------------------------------------------
// R22 hop K2: list-driven dual gather + attention + hop update.
__global__ __launch_bounds__(256) void upd_att_k(
    const int* __restrict__ nidx, const float* __restrict__ nval,
    const int* __restrict__ cnt,
    const unsigned short* __restrict__ hm, const unsigned short* __restrict__ Xh,
    const float* __restrict__ pa, const float* __restrict__ bc,
    const int* __restrict__ lens,
    const unsigned short* __restrict__ lh, unsigned short* __restrict__ lh_out) {
    int wv = threadIdx.x >> 6, lane = threadIdx.x & 63;
    int row = blockIdx.x * 4 + wv;
    int b = row / Nn, i = row - b * Nn;
    int d0 = lane * 8;
    if (i >= lens[b]) {
        bf16x8_t zz = {0, 0, 0, 0, 0, 0, 0, 0};
        *(bf16x8_t*)(lh_out + (size_t)row * ENC + d0) = zz;
        return;
    }
    const unsigned short* hmb = hm + (size_t)b * Nn * ENC;
    const unsigned short* Xhb = Xh + (size_t)b * Nn * 512;

    float ua[8], xa[8];
    {
        bf16x8_t h = *(const bf16x8_t*)(hmb + (size_t)i * ENC + d0);
        bf16x8_t x = *(const bf16x8_t*)(Xhb + (size_t)i * 512 + d0);
#pragma unroll
        for (int j = 0; j < 8; ++j) {
            ua[j] = bf2f((unsigned short)h[j]);
            xa[j] = bf2f((unsigned short)x[j]);
        }
    }
    const int* ni = nidx + (size_t)row * NLCAP;
    const float* nv = nval + (size_t)row * NLCAP;
    int cn = cnt[row];
    for (int e = 0; e < cn; e += 4) {
        int4 jj = *(const int4*)(ni + e);
        float4 vv = *(const float4*)(nv + e);
        bf16x8_t h0 = *(const bf16x8_t*)(hmb + (size_t)jj.x * ENC + d0);
        bf16x8_t h1 = *(const bf16x8_t*)(hmb + (size_t)jj.y * ENC + d0);
        bf16x8_t h2 = *(const bf16x8_t*)(hmb + (size_t)jj.z * ENC + d0);
        bf16x8_t h3 = *(const bf16x8_t*)(hmb + (size_t)jj.w * ENC + d0);
        bf16x8_t x0 = *(const bf16x8_t*)(Xhb + (size_t)jj.x * 512 + d0);
        bf16x8_t x1 = *(const bf16x8_t*)(Xhb + (size_t)jj.y * 512 + d0);
        bf16x8_t x2 = *(const bf16x8_t*)(Xhb + (size_t)jj.z * 512 + d0);
        bf16x8_t x3 = *(const bf16x8_t*)(Xhb + (size_t)jj.w * 512 + d0);
#pragma unroll
        for (int k = 0; k < 8; ++k) {
            ua[k] += vv.x * bf2f((unsigned short)h0[k]) + vv.y * bf2f((unsigned short)h1[k]) +
                     vv.z * bf2f((unsigned short)h2[k]) + vv.w * bf2f((unsigned short)h3[k]);
            xa[k] += vv.x * bf2f((unsigned short)x0[k]) + vv.y * bf2f((unsigned short)x1[k]) +
                     vv.z * bf2f((unsigned short)x2[k]) + vv.w * bf2f((unsigned short)x3[k]);
        }
    }
    const float* pp = pa + (size_t)row * ENC + d0;
    float4 p0 = *(const float4*)pp, p1 = *(const float4*)(pp + 4);
    float4 c0 = *(const float4*)(bc + d0), c1 = *(const float4*)(bc + d0 + 4);
    float pk[8] = {p0.x, p0.y, p0.z, p0.w, p1.x, p1.y, p1.z, p1.w};
    float ck[8] = {c0.x, c0.y, c0.z, c0.w, c1.x, c1.y, c1.z, c1.w};
    bf16x8_t lr = *(const bf16x8_t*)(lh + (size_t)row * ENC + d0);
    float o[8];
#pragma unroll
    for (int k = 0; k < 8; ++k) {
        float a = sigmoidf_(xa[k] + pk[k] + ck[k]);   // rm=1 (valid row)
        float l = bf2f((unsigned short)lr[k]);
        o[k] = a * tanhf(ua[k]) + (1.0f - a) * l;
    }
    float4 o0 = make_float4(o[0], o[1], o[2], o[3]);
    float4 o1 = make_float4(o[4], o[5], o[6], o[7]);
    *(bf16x8_t*)(lh_out + (size_t)row * ENC + d0) = cvt8(o0, o1);
}

// ---------------------------------------------------------------------------
// R23: g @ W1 split-K partials via MFMA with on-the-fly g staging (no gbf).
// Grid (63, 2, 4); z = K-slice: 0: nc; 1: n2q; 2: nc*n2q; 3: nc*q2n[b].
// (R22's 63-block merged variant regressed: 2.5% occupancy, 80us. Width wins.)
__global__ __launch_bounds__(256) void gemm_final_k(
    const float* __restrict__ nc, const float* n2q,
    const float* __restrict__ q2n,
    const unsigned short* __restrict__ W1T, float* __restrict__ part) {
    __shared__ __align__(16) unsigned short As[8192], Bts[8192];
    f32x4_t z4 = {0.f, 0.f, 0.f, 0.f};
    f32x4_t acc[2][2] = {{z4, z4}, {z4, z4}};
    int zz = blockIdx.z;
    int m0 = blockIdx.x * 64, n0 = blockIdx.y * 64;
    const float* Ap  = (zz == 1) ? n2q : nc;
    const float* A2p = (zz == 2) ? n2q : ((zz == 3) ? q2n : nullptr);
    int a2m = (zz == 2) ? 1 : ((zz == 3) ? 2 : 0);
    mfma_core<2>(Ap, A2p, a2m, nullptr, ENC, 512, W1T + zz * 512, 2048,
                 m0, n0, 512, Bn * Nn, As, Bts, acc);
    EPI_SETUP
    constexpr int M = Bn * Nn;
#pragma unroll
    for (int nj = 0; nj < 2; ++nj) {
        int col = n0 + wn + nj * 16 + cidx;
#pragma unroll
        for (int mi = 0; mi < 2; ++mi) {
#pragma unroll
            for (int r = 0; r < 4; ++r) {
                int row = m0 + wm + mi * 16 + quad * 4 + r;
                if (row < M) part[((size_t)zz * M + row) * 128 + col] = acc[mi][nj][r];
            }
        }
    }
}

// ---------------------------------------------------------------------------
// raw[row] = b2 + sum_h tanh(sum_z part[z][row][h] + b1[h]) * W2[h]
__global__ __launch_bounds__(256) void final_reduce_k(const float* __restrict__ part,
                                                      const float* __restrict__ b1p,
                                                      const float* __restrict__ W2p,
                                                      const float* __restrict__ b2p,
                                                      float* __restrict__ raw) {
    constexpr int M = Bn * Nn;
    int wave = threadIdx.x >> 6, lane = threadIdx.x & 63;
    int row = blockIdx.x * 4 + wave;
    if (row >= M) return;
    float v0 = 0.f, v1 = 0.f;
#pragma unroll
    for (int s = 0; s < 4; ++s) {
        const float* pr = part + ((size_t)s * M + row) * 128;
        v0 += pr[lane];
        v1 += pr[lane + 64];
    }
    float p = tanhf(v0 + b1p[lane]) * W2p[lane] + tanhf(v1 + b1p[lane + 64]) * W2p[lane + 64];
    for (int off = 32; off; off >>= 1) p += __shfl_xor(p, off, 64);
    if (lane == 0) raw[row] = p + b2p[0];
}

// ---------------------------------------------------------------------------
// Fused sim -> softmax(q) -> nodes2query + rowmax.  One wave per n-row.
__global__ __launch_bounds__(256) void sim_fused_k(const unsigned short* __restrict__ lh,
                                                   const float* __restrict__ qc,
                                                   const float* __restrict__ wa,
                                                   const int* __restrict__ lens,
                                                   float* __restrict__ n2q,
                                                   float* __restrict__ rowmax) {
    __shared__ float qcs[Qn * ENC];
    __shared__ float qdot[32];
    int b = blockIdx.x;
    int t = threadIdx.x;
    const float* qcb = qc + (size_t)b * Qn * ENC;
    for (int i = t * 4; i < Qn * ENC; i += 1024) *(float4*)&qcs[i] = *(const float4*)&qcb[i];
    __syncthreads();
    {
        int q = t >> 3, j = t & 7;
        if (q < Qn) {
            float s = 0.f;
            for (int k = 0; k < 64; ++k) {
                int d = j + 8 * k;
                s += qcs[q * ENC + d] * wa[ENC + d];
            }
            s += __shfl_xor(s, 1, 64);
            s += __shfl_xor(s, 2, 64);
            s += __shfl_xor(s, 4, 64);
            if (j == 0) qdot[q] = s;
        }
    }
    __syncthreads();

    int wv = t >> 6, lane = t & 63;
    int n = blockIdx.y * 4 + wv;
    int dA = lane * 4;
    int dB = 256 + lane * 4;
    const bool valid = n < lens[b];

    float s_[Qn];
    if (valid) {
        const unsigned short* lrow = lh + ((size_t)b * Nn + n) * ENC;
        ushort4 ua = *(const ushort4*)(lrow + dA);
        ushort4 ub = *(const ushort4*)(lrow + dB);
        float lv[8] = {bf2f(ua.x), bf2f(ua.y), bf2f(ua.z), bf2f(ua.w),
                       bf2f(ub.x), bf2f(ub.y), bf2f(ub.z), bf2f(ub.w)};
        float ndp = 0.f;
        float lvs[8];
#pragma unroll
        for (int j = 0; j < 4; ++j) {
            ndp += lv[j] * wa[dA + j];
            lvs[j] = lv[j] * wa[2 * ENC + dA + j];
            ndp += lv[4 + j] * wa[dB + j];
            lvs[4 + j] = lv[4 + j] * wa[2 * ENC + dB + j];
        }
#pragma unroll
        for (int off = 32; off; off >>= 1) ndp += __shfl_xor(ndp, off, 64);

#pragma unroll
        for (int q = 0; q < Qn; ++q) {
            float4 qa = *(const float4*)(qcs + q * ENC + dA);
            float4 qb = *(const float4*)(qcs + q * ENC + dB);
            s_[q] = lvs[0] * qa.x + lvs[1] * qa.y + lvs[2] * qa.z + lvs[3] * qa.w +
                    lvs[4] * qb.x + lvs[5] * qb.y + lvs[6] * qb.z + lvs[7] * qb.w;
        }
#pragma unroll
        for (int q = 0; q < Qn; ++q) {
#pragma unroll
            for (int off = 32; off; off >>= 1) s_[q] += __shfl_xor(s_[q], off, 64);
        }
#pragma unroll
        for (int q = 0; q < Qn; ++q) s_[q] += ndp + qdot[q];
    } else {
#pragma unroll
        for (int q = 0; q < Qn; ++q) s_[q] = qdot[q];
    }

    float mx = -INFINITY;
#pragma unroll
    for (int q = 0; q < Qn; ++q) mx = fmaxf(mx, s_[q]);
    float sum = 0.f;
#pragma unroll
    for (int q = 0; q < Qn; ++q) { s_[q] = expf(s_[q] - mx); sum += s_[q]; }
    float inv = 1.0f / sum;
    float o[8] = {};
#pragma unroll
    for (int q = 0; q < Qn; ++q) {
        float4 qa = *(const float4*)(qcs + q * ENC + dA);
        float4 qb = *(const float4*)(qcs + q * ENC + dB);
        float p = s_[q] * inv;
        o[0] += p * qa.x; o[1] += p * qa.y; o[2] += p * qa.z; o[3] += p * qa.w;
        o[4] += p * qb.x; o[5] += p * qb.y; o[6] += p * qb.z; o[7] += p * qb.w;
    }
    float* orow = n2q + ((size_t)b * Nn + n) * ENC;
    *(float4*)(orow + dA) = make_float4(o[0], o[1], o[2], o[3]);
    *(float4*)(orow + dB) = make_float4(o[4], o[5], o[6], o[7]);
    if (lane == 0) rowmax[b * Nn + n] = mx;
}

// ---------------------------------------------------------------------------
// Fused bvec (softmax over rowmax) + q2n (bvec-weighted sum of nc).
__global__ __launch_bounds__(512) void bvec_q2n_k(const float* __restrict__ rowmax,
                                                  const float* __restrict__ nc,
                                                  float* __restrict__ q2n) {
    __shared__ float red[8];
    __shared__ float bvs[512];
    int b = blockIdx.x, t = threadIdx.x;
    float v = (t < Nn) ? rowmax[b * Nn + t] : -INFINITY;
    float m = v;
    for (int off = 32; off; off >>= 1) m = fmaxf(m, __shfl_xor(m, off, 64));
    if ((t & 63) == 0) red[t >> 6] = m;
    __syncthreads();
    float bm = red[0];
    for (int i = 1; i < 8; ++i) bm = fmaxf(bm, red[i]);
    float e = (t < Nn) ? expf(v - bm) : 0.0f;
    float ssum = e;
    for (int off = 32; off; off >>= 1) ssum += __shfl_xor(ssum, off, 64);
    __syncthreads();
    if ((t & 63) == 0) red[t >> 6] = ssum;
    __syncthreads();
    float tot = 0.f;
    for (int i = 0; i < 8; ++i) tot += red[i];
    bvs[t] = e / tot;
    __syncthreads();
    const float* ncb = nc + (size_t)b * Nn * ENC;
    float acc = 0.f;
    for (int n = 0; n < Nn; ++n) acc = fmaf(bvs[n], ncb[(size_t)n * ENC + t], acc);
    q2n[b * ENC + t] = acc;
}

// ---------------------------------------------------------------------------
__global__ __launch_bounds__(256) void predmax_k(const int* __restrict__ mask,
                                                 const float* __restrict__ raw,
                                                 float* __restrict__ out) {
    int idx = blockIdx.x * 4 + (threadIdx.x >> 6);
    int lane = threadIdx.x & 63;
    if (idx >= Bn * NCn) return;
    int b = idx / NCn, c = idx - b * NCn;
    const int* mrow = mask + ((size_t)b * NCn + c) * Nn;
    const float* rrow = raw + (size_t)b * Nn;
    float mx = -INFINITY;
    for (int n = lane; n < Nn; n += 64) {
        float v = mrow[n] ? rrow[n] : 0.0f;
        if (v == 0.0f) v = -1.0e6f;
        mx = fmaxf(mx, v);
    }
    for (int off = 32; off; off >>= 1) mx = fmaxf(mx, __shfl_xor(mx, off, 64));
    if (lane == 0) out[idx] = mx;
}

}  // namespace

extern "C" void kernel_launch(void* const* d_in, const int* in_sizes, int n_in,
                              void* d_out, int out_size, void* d_ws, size_t ws_size,
                              hipStream_t stream) {
    const float* nodes_glove  = (const float*)d_in[0];
    const float* query_glove  = (const float*)d_in[1];
    const float* adj          = (const float*)d_in[2];
    const int*   nodes_length = (const int*)d_in[3];
    const int*   maskp        = (const int*)d_in[4];
    const float* Wn = (const float*)d_in[5];
    const float* bn = (const float*)d_in[6];
    const float* Wq = (const float*)d_in[7];
    const float* bq = (const float*)d_in[8];
    const float* Wh = (const float*)d_in[9];
    const float* bh = (const float*)d_in[10];
    const float* Wc = (const float*)d_in[11];
    const float* bc = (const float*)d_in[12];
    const float* wa = (const float*)d_in[13];
    const float* W1 = (const float*)d_in[14];
    const float* b1 = (const float*)d_in[15];
    const float* W2 = (const float*)d_in[16];
    const float* b2 = (const float*)d_in[17];
    float* out = (float*)d_out;

    float* ws = (float*)d_ws;
    size_t off = 0;
    auto alloc = [&](size_t n) { float* p = ws + off; off += n; return p; };
    constexpr size_t ME  = (size_t)Bn * Nn * ENC;       // 2,048,000 fp32 elems
    constexpr size_t MEH = ME / 2;
    float* nc   = alloc(ME);
    float* Asum = alloc(ME);       // fp32 adjacency; aliased as n2q after hops
    float* pa   = alloc(ME);       // fp32 partial att logits (lh @ Wc_lo)
    float* part = alloc(ME);       // split-K partials (own buffer; n2q aliases Asum)
    unsigned short* lh0 = (unsigned short*)alloc(MEH);
    unsigned short* lh1 = (unsigned short*)alloc(MEH);
    unsigned short* hm  = (unsigned short*)alloc(MEH);
    unsigned short* Xh  = (unsigned short*)alloc(MEH);  // bf16 X (R22)
    float* qc   = alloc((size_t)Bn * Qn * ENC);
    float* rowmax = alloc(Bn * Nn);
    float* q2n    = alloc(Bn * ENC);
    float* raw    = alloc(Bn * Nn);
    float* bhc2   = alloc(512);
    int*   nidx = (int*)alloc((size_t)Bn * Nn * NLCAP);   // R22 neighbor lists
    float* nval = alloc((size_t)Bn * Nn * NLCAP);
    int*   cntp = (int*)alloc(Bn * Nn);
    unsigned short* WnT  = (unsigned short*)alloc((size_t)ENC * 320 / 2);
    unsigned short* WqT  = (unsigned short*)alloc((size_t)ENC * 320 / 2);
    unsigned short* WhcT = (unsigned short*)alloc((size_t)1536 * 512 / 2);
    unsigned short* WcHiT = (unsigned short*)alloc((size_t)512 * 512 / 2);
    unsigned short* W1T  = (unsigned short*)alloc((size_t)128 * 2048 / 2);
    alloc(16384);  // tail pad
    float* n2q = Asum;             // after hops

    constexpr int M = Bn * Nn;  // 4000

    // 1. Fused prep: Asum (z=1) + weight transposes (z=0).
    prep_k<<<dim3(2048, 1, 2), 256, 0, stream>>>(adj, Asum, Wn, Wq, Wh, Wc, W1,
                                                 WnT, WqT, WhcT, WcHiT, W1T);

    // 2. Fused input GEMMs + Whc2 + bhc2 + neighbor lists (1601 blocks).
    gemm_in_k<<<dim3(1601), 256, 0, stream>>>(nodes_glove, query_glove, Wh, Wc, bh,
                                              Asum, WnT, WqT, WcHiT, bn, bq,
                                              nodes_length, nc, lh0, qc, WhcT, bhc2,
                                              nidx, nval, cntp);

    // 3-8. 3 hops x 2 dispatches.
    unsigned short* cur = lh0;
    unsigned short* nxt = lh1;
    for (int h = 0; h < 3; ++h) {
        gemm_hop_k<<<dim3(63, 24), 256, 0, stream>>>(cur, WhcT, bh, bhc2,
                                                     nodes_length, hm, pa, Xh);
        upd_att_k<<<dim3(M / 4), 256, 0, stream>>>(nidx, nval, cntp, hm, Xh, pa, bc,
                                                   nodes_length, cur, nxt);
        unsigned short* tmp = cur; cur = nxt; nxt = tmp;
    }
    // cur == lh1 == final last_hop.

    // 9-13. Tail (split-K final GEMM restored for width; R22 merge regressed).
    sim_fused_k<<<dim3(Bn, 125), 256, 0, stream>>>(cur, qc, wa, nodes_length, n2q, rowmax);
    bvec_q2n_k<<<dim3(Bn), 512, 0, stream>>>(rowmax, nc, q2n);
    gemm_final_k<<<dim3((M + 63) / 64, 2, 4), 256, 0, stream>>>(nc, n2q, q2n, W1T, part);
    final_reduce_k<<<dim3((M + 3) / 4), 256, 0, stream>>>(part, b1, W2, b2, raw);
    predmax_k<<<dim3((Bn * NCn + 3) / 4), 256, 0, stream>>>(maskp, raw, out);
}